// Round 4
// baseline (341.020 us; speedup 1.0000x reference)
//
#include <hip/hip_runtime.h>
#include <hip/hip_bf16.h>

// Flash attention fwd, masked, fp32 I/O, bf16 MFMA compute.
// n=8 heads, q=s=4096, d=v=64.
// S^T = K·Q^T (lane owns one q-column); PV computes O^T = V^T·P^T.
// Round 4: prepacked bf16 K / V^T "LDS images" in d_ws (swizzled byte order),
// staged via global_load_lds into a 4-deep LDS ring, counted vmcnt(16) + raw
// s_barrier (1/chunk), mask prefetched 3 ahead in registers, head-per-XCD grid.

#define NHEADS 8
#define QLEN   4096
#define SLEN   4096
#define DDIM   64
#define VDIM   64
#define SBLK   64
#define QBLK   64
#define NWAVES 4
#define NCHUNK (SLEN / SBLK)
#define IMG_CHUNK_BYTES 16384   // 8KB K + 8KB V^T per (head,chunk)
#define IMG_OFFSET 256

typedef __bf16          bf16x4 __attribute__((ext_vector_type(4)));
typedef __bf16          bf16x8 __attribute__((ext_vector_type(8)));
typedef float           f32x4  __attribute__((ext_vector_type(4)));
typedef unsigned int    u32x4  __attribute__((ext_vector_type(4)));
typedef unsigned short  u16x4  __attribute__((ext_vector_type(4)));

// ---------------- mask dtype detection (u8 vs i32 vs f32) ----------------
__global__ void detect_mask_kernel(const unsigned char* __restrict__ M,
                                   int* __restrict__ flag) {
  __shared__ int or12, or0;
  if (threadIdx.x == 0) { or12 = 0; or0 = 0; }
  __syncthreads();
  int v12 = 0, v0 = 0;
  for (int i = threadIdx.x; i < 1024; i += 256) {
    v12 |= M[4 * i + 1] | M[4 * i + 2];
    v0  |= M[4 * i + 0];
  }
  atomicOr(&or12, v12);
  atomicOr(&or0, v0);
  __syncthreads();
  if (threadIdx.x == 0)
    *flag = (or12 == 0) ? 1 : ((or0 == 0) ? 2 : 0);   // 1=i32, 2=f32, 0=u8
}

// ---------------- prepack: K -> bf16, V -> V^T bf16, swizzled image ----------------
// Image block (h,c): bytes [0,8192) = K chunk laid out as LDS expects
// (off = (srow*128 + d0*2) ^ ((srow&7)<<4)); bytes [8192,16384) = V^T
// (off = (vv*128 + s4*2) ^ ((vv&7)<<4)). Main kernel stages with linear
// global_load_lds, so LDS content == image content (rule: both-sides swizzle).
__global__ __launch_bounds__(256)
void prepack_kv(const float* __restrict__ Kg, const float* __restrict__ Vg,
                unsigned char* __restrict__ img) {
  const int c = blockIdx.x, h = blockIdx.y, t = threadIdx.x;
  const float* Kp = Kg + ((size_t)h * SLEN + (size_t)c * SBLK) * DDIM;
  const float* Vp = Vg + ((size_t)h * SLEN + (size_t)c * SBLK) * VDIM;
  unsigned char* out = img + (size_t)(h * NCHUNK + c) * IMG_CHUNK_BYTES;
#pragma unroll
  for (int it = 0; it < 4; ++it) {
    int srow = (t >> 4) + it * 16;
    int d0   = (t & 15) * 4;
    f32x4 kv = *(const f32x4*)(Kp + (size_t)srow * DDIM + d0);
    bf16x4 kb;
#pragma unroll
    for (int j = 0; j < 4; ++j) kb[j] = (__bf16)kv[j];
    int off = (srow * 128 + d0 * 2) ^ ((srow & 7) << 4);
    *(u16x4*)(out + off) = __builtin_bit_cast(u16x4, kb);
  }
#pragma unroll
  for (int it = 0; it < 4; ++it) {
    int vv = (t >> 4) + it * 16;
    int s4 = (t & 15) * 4;
    const float* vp = Vp + (size_t)s4 * VDIM + vv;
    bf16x4 vb;
    vb[0] = (__bf16)vp[0];        vb[1] = (__bf16)vp[VDIM];
    vb[2] = (__bf16)vp[2 * VDIM]; vb[3] = (__bf16)vp[3 * VDIM];
    int off = 8192 + ((vv * 128 + s4 * 2) ^ ((vv & 7) << 4));
    *(u16x4*)(out + off) = __builtin_bit_cast(u16x4, vb);
  }
}

// ---------------- async global->LDS helper ----------------
__device__ __forceinline__ void gl16(const unsigned char* g, unsigned char* l) {
  __builtin_amdgcn_global_load_lds(
      (const __attribute__((address_space(1))) unsigned int*)g,
      (__attribute__((address_space(3))) unsigned int*)l, 16, 0, 0);
}

// ---------------- fast path (u8 mask) ----------------
__global__ __launch_bounds__(256, 2)
void attn_fwd_fast(const float* __restrict__ Qg, const unsigned char* __restrict__ Mg,
                   const unsigned char* __restrict__ img, float* __restrict__ Og,
                   const int* __restrict__ mflag)
{
  __shared__ __align__(16) unsigned char KV[4][IMG_CHUNK_BYTES];   // ring: K at +0, V^T at +8192
  __shared__ __align__(16) unsigned short Psh[NWAVES][16 * 64];

  const int mfmt = *mflag;
  if (mfmt != 0) return;          // non-u8 handled by fallback kernel

  const int tid  = threadIdx.x;
  const int wave = tid >> 6;
  const int lane = tid & 63;
  const int g    = lane >> 4;
  const int lq   = lane & 15;

  const int head = blockIdx.x;    // grid (8, 64): id%8 == head -> one XCD per head
  const int qblk = blockIdx.y;

  const float* Qp = Qg + ((size_t)head * QLEN + (size_t)qblk * QBLK) * DDIM;
  float* Op = Og + ((size_t)head * QLEN + (size_t)qblk * QBLK) * DDIM;
  const unsigned char* imgh = img + (size_t)head * NCHUNK * IMG_CHUNK_BYTES;

  // Q fragments, pre-scaled by (1/sqrt(d))*log2(e)
  const float QSCALE = 0.125f * 1.44269504f;
  const int qrow = wave * 16 + lq;
  bf16x8 qf[2];
#pragma unroll
  for (int ks = 0; ks < 2; ++ks) {
    const float* qp = Qp + (size_t)qrow * DDIM + 8 * g + 32 * ks;
    f32x4 a = *(const f32x4*)qp;
    f32x4 b = *(const f32x4*)(qp + 4);
    bf16x8 t;
#pragma unroll
    for (int j = 0; j < 4; ++j) { t[j] = (__bf16)(a[j] * QSCALE); t[4 + j] = (__bf16)(b[j] * QSCALE); }
    qf[ks] = t;
  }

  const unsigned char* mrow8 = Mg + ((size_t)head * QLEN + (size_t)qblk * QBLK + qrow) * SLEN;

  f32x4 oacc[4];
#pragma unroll
  for (int vt = 0; vt < 4; ++vt) oacc[vt] = (f32x4){0.f, 0.f, 0.f, 0.f};
  float m_run = -INFINITY;
  float l_run = 0.f;

#define STAGE(CM, BUF) {                                                       \
  int cm_ = (CM); if (cm_ > NCHUNK - 1) cm_ = NCHUNK - 1;                      \
  const unsigned char* s_ = imgh + (size_t)cm_ * IMG_CHUNK_BYTES + wave * 2048 + lane * 16; \
  unsigned char* d_ = &KV[BUF][wave * 2048];                                   \
  gl16(s_,        d_);                                                         \
  gl16(s_ + 1024, d_ + 1024);                                                  \
  gl16(s_ + 8192, d_ + 8192);                                                  \
  gl16(s_ + 9216, d_ + 9216);                                                  \
}

#define LOAD_MASK_F(MS, CM) {                                                  \
  int cm_ = (CM); if (cm_ > NCHUNK - 1) cm_ = NCHUNK - 1;                      \
  size_t mo_ = (size_t)cm_ * SBLK;                                             \
  _Pragma("unroll")                                                            \
  for (int st = 0; st < 4; ++st)                                               \
    MS[st] = *(const unsigned*)(mrow8 + mo_ + 16 * st + 4 * g);                \
}

// Body c: wait for its stage (counted, never 0), barrier, then issue c+3's
// mask+stage, then compute. vmcnt(16) is order-robust: ops in-order-retire and
// >=16 newer vmem ops (2 full later regions) exist behind G(c) in any
// intra-region issue order.
#define FBODY(C, BUF, MUSE, MLOAD) {                                           \
  asm volatile("s_waitcnt vmcnt(16)" ::: "memory");                            \
  __builtin_amdgcn_s_barrier();                                                \
  LOAD_MASK_F(MLOAD, (C) + 3);                                                 \
  STAGE((C) + 3, ((BUF) + 3) & 3);                                             \
  const char* kbase_ = (const char*)KV[BUF];                                   \
  f32x4 sacc[4];                                                               \
  _Pragma("unroll")                                                            \
  for (int st = 0; st < 4; ++st) sacc[st] = (f32x4){0.f, 0.f, 0.f, 0.f};       \
  _Pragma("unroll")                                                            \
  for (int st = 0; st < 4; ++st) {                                             \
    int srow = lq + 16 * st;                                                   \
    _Pragma("unroll")                                                          \
    for (int ks = 0; ks < 2; ++ks) {                                           \
      int off = (srow * 128 + (8 * g + 32 * ks) * 2) ^ ((srow & 7) << 4);      \
      bf16x8 kf = *(const bf16x8*)(kbase_ + off);                              \
      sacc[st] = __builtin_amdgcn_mfma_f32_16x16x32_bf16(kf, qf[ks], sacc[st], 0, 0, 0); \
    }                                                                          \
  }                                                                            \
  float vals[4][4];                                                            \
  float mloc = -INFINITY;                                                      \
  _Pragma("unroll")                                                            \
  for (int st = 0; st < 4; ++st) {                                             \
    _Pragma("unroll")                                                          \
    for (int r = 0; r < 4; ++r) {                                              \
      bool keep = ((MUSE[st] >> (8 * r)) & 0xFFu) != 0u;                       \
      float v = keep ? sacc[st][r] : -1.0e9f;                                  \
      vals[st][r] = v;                                                         \
      mloc = fmaxf(mloc, v);                                                   \
    }                                                                          \
  }                                                                            \
  mloc = fmaxf(mloc, __shfl_xor(mloc, 16));                                    \
  mloc = fmaxf(mloc, __shfl_xor(mloc, 32));                                    \
  float m_new = fmaxf(m_run, mloc);                                            \
  float alpha = __builtin_amdgcn_exp2f(m_run - m_new);                         \
  float lsum = 0.f;                                                            \
  _Pragma("unroll")                                                            \
  for (int st = 0; st < 4; ++st) {                                             \
    bf16x4 pb;                                                                 \
    _Pragma("unroll")                                                          \
    for (int r = 0; r < 4; ++r) {                                              \
      float p = __builtin_amdgcn_exp2f(vals[st][r] - m_new);                   \
      lsum += p;                                                               \
      pb[r] = (__bf16)p;                                                       \
    }                                                                          \
    int poff = (lq * 128 + (16 * st + 4 * g) * 2) ^ ((lq & 7) << 4);           \
    *(u16x4*)((char*)Psh[wave] + poff) = __builtin_bit_cast(u16x4, pb);        \
  }                                                                            \
  lsum += __shfl_xor(lsum, 16);                                                \
  lsum += __shfl_xor(lsum, 32);                                                \
  l_run = l_run * alpha + lsum;                                                \
  m_run = m_new;                                                               \
  _Pragma("unroll")                                                            \
  for (int vt = 0; vt < 4; ++vt) {                                             \
    _Pragma("unroll")                                                          \
    for (int r = 0; r < 4; ++r) oacc[vt][r] *= alpha;                          \
  }                                                                            \
  const char* vbase_ = (const char*)KV[BUF] + 8192;                            \
  _Pragma("unroll")                                                            \
  for (int ks = 0; ks < 2; ++ks) {                                             \
    int poff = (lq * 128 + (8 * g + 32 * ks) * 2) ^ ((lq & 7) << 4);           \
    bf16x8 pf = *(const bf16x8*)((const char*)Psh[wave] + poff);               \
    _Pragma("unroll")                                                          \
    for (int vt = 0; vt < 4; ++vt) {                                           \
      int vrow = lq + 16 * vt;                                                 \
      int voff = (vrow * 128 + (8 * g + 32 * ks) * 2) ^ ((vrow & 7) << 4);     \
      bf16x8 vf = *(const bf16x8*)(vbase_ + voff);                             \
      oacc[vt] = __builtin_amdgcn_mfma_f32_16x16x32_bf16(vf, pf, oacc[vt], 0, 0, 0); \
    }                                                                          \
  }                                                                            \
}

  unsigned mA[4], mB[4], mC[4], mD[4];

  // prologue: 3 regions, fenced so vmcnt accounting holds in any intra-region order
  __builtin_amdgcn_sched_barrier(0);
  LOAD_MASK_F(mA, 0); STAGE(0, 0);
  asm volatile("" ::: "memory");
  LOAD_MASK_F(mB, 1); STAGE(1, 1);
  asm volatile("" ::: "memory");
  LOAD_MASK_F(mC, 2); STAGE(2, 2);

  for (int cc = 0; cc < NCHUNK; cc += 4) {
    FBODY(cc + 0, 0, mA, mD);
    FBODY(cc + 1, 1, mB, mA);
    FBODY(cc + 2, 2, mC, mB);
    FBODY(cc + 3, 3, mD, mC);
  }

  float inv_l = 1.0f / l_run;
  float* orow = Op + (size_t)qrow * VDIM;
#pragma unroll
  for (int vt = 0; vt < 4; ++vt) {
    f32x4 o;
#pragma unroll
    for (int r = 0; r < 4; ++r) o[r] = oacc[vt][r] * inv_l;
    *(f32x4*)(orow + 16 * vt + 4 * g) = o;
  }
#undef STAGE
#undef LOAD_MASK_F
#undef FBODY
}

// ---------------- fallback (round-3 kernel, gated) ----------------
struct MaskRegs {
  unsigned w8[4];
  u32x4    w32[4];
};

__global__ __launch_bounds__(256, 2)
void attn_fwd_fallback(const float* __restrict__ Qg, const float* __restrict__ Kg,
                       const float* __restrict__ Vg, const unsigned char* __restrict__ Mg,
                       float* __restrict__ Og, const int* __restrict__ mflag, int gate)
{
  __shared__ __align__(16) unsigned short Ksh[2][64 * 64];
  __shared__ __align__(16) unsigned short Vsh[2][64 * 64];
  __shared__ __align__(16) unsigned short Psh[NWAVES][16 * 64];

  const int mfmt = *mflag;
  if (gate && mfmt == 0) return;   // u8 handled by fast kernel

  const int tid  = threadIdx.x;
  const int wave = tid >> 6;
  const int lane = tid & 63;
  const int g    = lane >> 4;
  const int lq   = lane & 15;

  const int head = blockIdx.y;
  const int qblk = blockIdx.x;

  const float* Qp = Qg + ((size_t)head * QLEN + (size_t)qblk * QBLK) * DDIM;
  const float* Kp = Kg + (size_t)head * SLEN * DDIM;
  const float* Vp = Vg + (size_t)head * SLEN * VDIM;
  float* Op = Og + ((size_t)head * QLEN + (size_t)qblk * QBLK) * DDIM;

  const float QSCALE = 0.125f * 1.44269504f;
  const int qrow = wave * 16 + lq;
  bf16x8 qf[2];
#pragma unroll
  for (int ks = 0; ks < 2; ++ks) {
    const float* qp = Qp + (size_t)qrow * DDIM + 8 * g + 32 * ks;
    f32x4 a = *(const f32x4*)qp;
    f32x4 b = *(const f32x4*)(qp + 4);
    bf16x8 t;
#pragma unroll
    for (int j = 0; j < 4; ++j) { t[j] = (__bf16)(a[j] * QSCALE); t[4 + j] = (__bf16)(b[j] * QSCALE); }
    qf[ks] = t;
  }

  const size_t mrow_elems = ((size_t)head * QLEN + (size_t)qblk * QBLK + qrow) * SLEN;
  const unsigned char* mrow8  = Mg + mrow_elems;
  const unsigned*      mrow32 = (const unsigned*)Mg + mrow_elems;

  f32x4 oacc[4];
#pragma unroll
  for (int vt = 0; vt < 4; ++vt) oacc[vt] = (f32x4){0.f, 0.f, 0.f, 0.f};
  float m_run = -INFINITY;
  float l_run = 0.f;

#define PREFETCH_KV(S0)                                                        \
  _Pragma("unroll")                                                            \
  for (int it = 0; it < 4; ++it) {                                             \
    int srow = (tid >> 4) + it * 16;                                           \
    kpre[it] = *(const f32x4*)(Kp + (size_t)((S0) + srow) * DDIM + (tid & 15) * 4); \
  }                                                                            \
  _Pragma("unroll")                                                            \
  for (int it = 0; it < 4; ++it) {                                             \
    int vv = (tid >> 4) + it * 16;                                             \
    const float* vp = Vp + (size_t)((S0) + (tid & 15) * 4) * VDIM + vv;        \
    vpre[it][0] = vp[0]; vpre[it][1] = vp[VDIM];                               \
    vpre[it][2] = vp[2 * VDIM]; vpre[it][3] = vp[3 * VDIM];                    \
  }

#define WRITE_KV(BUF)                                                          \
  _Pragma("unroll")                                                            \
  for (int it = 0; it < 4; ++it) {                                             \
    int srow = (tid >> 4) + it * 16;                                           \
    int d0   = (tid & 15) * 4;                                                 \
    bf16x4 kb;                                                                 \
    _Pragma("unroll") for (int j = 0; j < 4; ++j) kb[j] = (__bf16)kpre[it][j]; \
    int off = (srow * 128 + d0 * 2) ^ ((srow & 7) << 4);                       \
    *(u16x4*)((char*)Ksh[BUF] + off) = __builtin_bit_cast(u16x4, kb);          \
  }                                                                            \
  _Pragma("unroll")                                                            \
  for (int it = 0; it < 4; ++it) {                                             \
    int vv = (tid >> 4) + it * 16;                                             \
    int s4 = (tid & 15) * 4;                                                   \
    bf16x4 vb;                                                                 \
    _Pragma("unroll") for (int j = 0; j < 4; ++j) vb[j] = (__bf16)vpre[it][j]; \
    int off = (vv * 128 + s4 * 2) ^ ((vv & 7) << 4);                           \
    *(u16x4*)((char*)Vsh[BUF] + off) = __builtin_bit_cast(u16x4, vb);          \
  }

#define LOAD_MASK(MR, S0)                                                      \
  if (mfmt == 0) {                                                             \
    _Pragma("unroll")                                                          \
    for (int st = 0; st < 4; ++st)                                             \
      MR.w8[st] = *(const unsigned*)(mrow8 + (S0) + 16 * st + 4 * g);          \
  } else {                                                                     \
    _Pragma("unroll")                                                          \
    for (int st = 0; st < 4; ++st)                                             \
      MR.w32[st] = *(const u32x4*)(mrow32 + (S0) + 16 * st + 4 * g);           \
  }

#define CHUNK_BODY(C, CUR, MUSE, MLOAD) {                                      \
  const bool hasn = ((C) + 1 < NCHUNK);                                        \
  f32x4 kpre[4]; float vpre[4][4];                                             \
  if (hasn) {                                                                  \
    const int s0n = ((C) + 1) * SBLK;                                          \
    PREFETCH_KV(s0n);                                                          \
    LOAD_MASK(MLOAD, s0n);                                                     \
  }                                                                            \
  f32x4 sacc[4];                                                               \
  _Pragma("unroll")                                                            \
  for (int st = 0; st < 4; ++st) sacc[st] = (f32x4){0.f, 0.f, 0.f, 0.f};       \
  _Pragma("unroll")                                                            \
  for (int st = 0; st < 4; ++st) {                                             \
    int srow = lq + 16 * st;                                                   \
    _Pragma("unroll")                                                          \
    for (int ks = 0; ks < 2; ++ks) {                                           \
      int off = (srow * 128 + (8 * g + 32 * ks) * 2) ^ ((srow & 7) << 4);      \
      bf16x8 kf = *(const bf16x8*)((const char*)Ksh[CUR] + off);               \
      sacc[st] = __builtin_amdgcn_mfma_f32_16x16x32_bf16(kf, qf[ks], sacc[st], 0, 0, 0); \
    }                                                                          \
  }                                                                            \
  float vals[4][4];                                                            \
  float mloc = -INFINITY;                                                      \
  _Pragma("unroll")                                                            \
  for (int st = 0; st < 4; ++st) {                                             \
    bool keep[4];                                                              \
    if (mfmt == 0) {                                                           \
      _Pragma("unroll")                                                        \
      for (int r = 0; r < 4; ++r) keep[r] = ((MUSE.w8[st] >> (8 * r)) & 0xFFu) != 0u; \
    } else {                                                                   \
      _Pragma("unroll")                                                        \
      for (int r = 0; r < 4; ++r) keep[r] = MUSE.w32[st][r] != 0u;             \
    }                                                                          \
    _Pragma("unroll")                                                          \
    for (int r = 0; r < 4; ++r) {                                              \
      float v = keep[r] ? sacc[st][r] : -1.0e9f;                               \
      vals[st][r] = v;                                                         \
      mloc = fmaxf(mloc, v);                                                   \
    }                                                                          \
  }                                                                            \
  mloc = fmaxf(mloc, __shfl_xor(mloc, 16));                                    \
  mloc = fmaxf(mloc, __shfl_xor(mloc, 32));                                    \
  float m_new = fmaxf(m_run, mloc);                                            \
  float alpha = __builtin_amdgcn_exp2f(m_run - m_new);                         \
  float lsum = 0.f;                                                            \
  _Pragma("unroll")                                                            \
  for (int st = 0; st < 4; ++st) {                                             \
    bf16x4 pb;                                                                 \
    _Pragma("unroll")                                                          \
    for (int r = 0; r < 4; ++r) {                                              \
      float p = __builtin_amdgcn_exp2f(vals[st][r] - m_new);                   \
      lsum += p;                                                               \
      pb[r] = (__bf16)p;                                                       \
    }                                                                          \
    int off = (lq * 128 + (16 * st + 4 * g) * 2) ^ ((lq & 7) << 4);            \
    *(u16x4*)((char*)Psh[wave] + off) = __builtin_bit_cast(u16x4, pb);         \
  }                                                                            \
  lsum += __shfl_xor(lsum, 16);                                                \
  lsum += __shfl_xor(lsum, 32);                                                \
  l_run = l_run * alpha + lsum;                                                \
  m_run = m_new;                                                               \
  _Pragma("unroll")                                                            \
  for (int vt = 0; vt < 4; ++vt) {                                             \
    _Pragma("unroll")                                                          \
    for (int r = 0; r < 4; ++r) oacc[vt][r] *= alpha;                          \
  }                                                                            \
  _Pragma("unroll")                                                            \
  for (int ks = 0; ks < 2; ++ks) {                                             \
    int poff = (lq * 128 + (8 * g + 32 * ks) * 2) ^ ((lq & 7) << 4);           \
    bf16x8 pf = *(const bf16x8*)((const char*)Psh[wave] + poff);               \
    _Pragma("unroll")                                                          \
    for (int vt = 0; vt < 4; ++vt) {                                           \
      int vrow = lq + 16 * vt;                                                 \
      int voff = (vrow * 128 + (8 * g + 32 * ks) * 2) ^ ((vrow & 7) << 4);     \
      bf16x8 vf = *(const bf16x8*)((const char*)Vsh[CUR] + voff);              \
      oacc[vt] = __builtin_amdgcn_mfma_f32_16x16x32_bf16(vf, pf, oacc[vt], 0, 0, 0); \
    }                                                                          \
  }                                                                            \
  if (hasn) { WRITE_KV((CUR) ^ 1); }                                           \
  __syncthreads();                                                             \
}

  MaskRegs mA, mB;
  {
    f32x4 kpre[4]; float vpre[4][4];
    PREFETCH_KV(0);
    LOAD_MASK(mA, 0);
    WRITE_KV(0);
    __syncthreads();
  }
  for (int cc = 0; cc < NCHUNK; cc += 2) {
    CHUNK_BODY(cc,     0, mA, mB);
    CHUNK_BODY(cc + 1, 1, mB, mA);
  }

  float inv_l = 1.0f / l_run;
  float* orow = Op + (size_t)qrow * VDIM;
#pragma unroll
  for (int vt = 0; vt < 4; ++vt) {
    f32x4 o;
#pragma unroll
    for (int r = 0; r < 4; ++r) o[r] = oacc[vt][r] * inv_l;
    *(f32x4*)(orow + 16 * vt + 4 * g) = o;
  }
#undef PREFETCH_KV
#undef WRITE_KV
#undef LOAD_MASK
#undef CHUNK_BODY
}

extern "C" void kernel_launch(void* const* d_in, const int* in_sizes, int n_in,
                              void* d_out, int out_size, void* d_ws, size_t ws_size,
                              hipStream_t stream) {
  const float* Qg = (const float*)d_in[0];
  const float* Kg = (const float*)d_in[1];
  const float* Vg = (const float*)d_in[2];
  const unsigned char* Mg = (const unsigned char*)d_in[3];
  float* Og = (float*)d_out;
  int* mflag = (int*)d_ws;
  unsigned char* img = (unsigned char*)d_ws + IMG_OFFSET;
  const size_t need = IMG_OFFSET + (size_t)NHEADS * NCHUNK * IMG_CHUNK_BYTES;

  detect_mask_kernel<<<1, 256, 0, stream>>>(Mg, mflag);

  if (ws_size >= need) {
    prepack_kv<<<dim3(NCHUNK, NHEADS), 256, 0, stream>>>(Kg, Vg, img);
    attn_fwd_fast<<<dim3(NHEADS, QLEN / QBLK), 256, 0, stream>>>(Qg, Mg, img, Og, mflag);
    // safety net: runs only if mask is not u8
    attn_fwd_fallback<<<dim3(QLEN / QBLK, NHEADS), 256, 0, stream>>>(Qg, Kg, Vg, Mg, Og, mflag, 1);
  } else {
    attn_fwd_fallback<<<dim3(QLEN / QBLK, NHEADS), 256, 0, stream>>>(Qg, Kg, Vg, Mg, Og, mflag, 0);
  }
}

// Round 5
// 331.950 us; speedup vs baseline: 1.0273x; 1.0273x over previous
//
#include <hip/hip_runtime.h>
#include <hip/hip_bf16.h>

// Flash attention fwd, masked, fp32 I/O, bf16 MFMA compute.
// n=8 heads, q=s=4096, d=v=64.
// S^T = K·Q^T (lane owns one q-column); PV computes O^T = V^T·P^T.
// Round 5: workspace need shrunk to EXACTLY 8 MiB (= probable ws_size):
// no flag in d_ws — mask dtype self-detected in-kernel. Fast path:
// prepacked bf16 K / V^T swizzled "LDS images" in d_ws, staged via
// global_load_lds into a 4-deep LDS ring, counted vmcnt(16) + raw s_barrier,
// mask prefetched 3 chunks ahead in registers, head-per-XCD grid.

#define NHEADS 8
#define QLEN   4096
#define SLEN   4096
#define DDIM   64
#define VDIM   64
#define SBLK   64
#define QBLK   64
#define NWAVES 4
#define NCHUNK (SLEN / SBLK)
#define IMG_CHUNK_BYTES 16384   // 8KB K + 8KB V^T per (head,chunk)

typedef __bf16          bf16x4 __attribute__((ext_vector_type(4)));
typedef __bf16          bf16x8 __attribute__((ext_vector_type(8)));
typedef float           f32x4  __attribute__((ext_vector_type(4)));
typedef unsigned int    u32x4  __attribute__((ext_vector_type(4)));
typedef unsigned short  u16x4  __attribute__((ext_vector_type(4)));

// ---------------- in-kernel mask dtype detection ----------------
// Wave-cooperative scan of the mask's first 1KB (64 lanes x 16B).
// i32 {0,1}: bytes 1,2 of every word are zero -> return 1.
// f32 {0,1.0f}: byte 0 of every word is zero (0x3F800000 LE) -> return 2.
// u8 bool: neither -> return 0.  Uniform across all lanes/waves/blocks.
__device__ __forceinline__ int detect_mfmt(const unsigned char* __restrict__ M) {
  const int lane = threadIdx.x & 63;
  u32x4 w = *((const u32x4*)M + lane);
  unsigned o = w[0] | w[1] | w[2] | w[3];
  unsigned comb = ((o & 0x00FFFF00u) ? 1u : 0u) | ((o & 0x000000FFu) ? 2u : 0u);
  comb |= __shfl_xor((int)comb, 1);  comb |= __shfl_xor((int)comb, 2);
  comb |= __shfl_xor((int)comb, 4);  comb |= __shfl_xor((int)comb, 8);
  comb |= __shfl_xor((int)comb, 16); comb |= __shfl_xor((int)comb, 32);
  return ((comb & 1u) == 0u) ? 1 : (((comb & 2u) == 0u) ? 2 : 0);
}

// ---------------- prepack: K -> bf16, V -> V^T bf16, swizzled image ----------------
// Image block (h,c): bytes [0,8192) = K chunk in LDS byte order
// (off = (srow*128 + d0*2) ^ ((srow&7)<<4)); bytes [8192,16384) = V^T
// (off = (vv*128 + s4*2) ^ ((vv&7)<<4)). Main kernel stages linearly with
// global_load_lds, so LDS content == image content (both-sides swizzle rule).
__global__ __launch_bounds__(256)
void prepack_kv(const float* __restrict__ Kg, const float* __restrict__ Vg,
                unsigned char* __restrict__ img) {
  const int c = blockIdx.x, h = blockIdx.y, t = threadIdx.x;
  const float* Kp = Kg + ((size_t)h * SLEN + (size_t)c * SBLK) * DDIM;
  const float* Vp = Vg + ((size_t)h * SLEN + (size_t)c * SBLK) * VDIM;
  unsigned char* out = img + (size_t)(h * NCHUNK + c) * IMG_CHUNK_BYTES;
#pragma unroll
  for (int it = 0; it < 4; ++it) {
    int srow = (t >> 4) + it * 16;
    int d0   = (t & 15) * 4;
    f32x4 kv = *(const f32x4*)(Kp + (size_t)srow * DDIM + d0);
    bf16x4 kb;
#pragma unroll
    for (int j = 0; j < 4; ++j) kb[j] = (__bf16)kv[j];
    int off = (srow * 128 + d0 * 2) ^ ((srow & 7) << 4);
    *(u16x4*)(out + off) = __builtin_bit_cast(u16x4, kb);
  }
#pragma unroll
  for (int it = 0; it < 4; ++it) {
    int vv = (t >> 4) + it * 16;
    int s4 = (t & 15) * 4;
    const float* vp = Vp + (size_t)s4 * VDIM + vv;
    bf16x4 vb;
    vb[0] = (__bf16)vp[0];        vb[1] = (__bf16)vp[VDIM];
    vb[2] = (__bf16)vp[2 * VDIM]; vb[3] = (__bf16)vp[3 * VDIM];
    int off = 8192 + ((vv * 128 + s4 * 2) ^ ((vv & 7) << 4));
    *(u16x4*)(out + off) = __builtin_bit_cast(u16x4, vb);
  }
}

// ---------------- async global->LDS helper ----------------
__device__ __forceinline__ void gl16(const unsigned char* g, unsigned char* l) {
  __builtin_amdgcn_global_load_lds(
      (const __attribute__((address_space(1))) unsigned int*)g,
      (__attribute__((address_space(3))) unsigned int*)l, 16, 0, 0);
}

// ---------------- fast path (u8 mask; others -> fallback) ----------------
__global__ __launch_bounds__(256, 2)
void attn_fwd_fast(const float* __restrict__ Qg, const unsigned char* __restrict__ Mg,
                   const unsigned char* __restrict__ img, float* __restrict__ Og)
{
  __shared__ __align__(16) unsigned char KV[4][IMG_CHUNK_BYTES];   // ring: K at +0, V^T at +8192
  __shared__ __align__(16) unsigned short Psh[NWAVES][16 * 64];

  if (detect_mfmt(Mg) != 0) return;   // uniform; non-u8 handled by fallback kernel

  const int tid  = threadIdx.x;
  const int wave = tid >> 6;
  const int lane = tid & 63;
  const int g    = lane >> 4;
  const int lq   = lane & 15;

  const int head = blockIdx.x;    // grid (8, 64): linear id % 8 == head -> one XCD per head
  const int qblk = blockIdx.y;

  const float* Qp = Qg + ((size_t)head * QLEN + (size_t)qblk * QBLK) * DDIM;
  float* Op = Og + ((size_t)head * QLEN + (size_t)qblk * QBLK) * DDIM;
  const unsigned char* imgh = img + (size_t)head * NCHUNK * IMG_CHUNK_BYTES;

  // Q fragments, pre-scaled by (1/sqrt(d))*log2(e)
  const float QSCALE = 0.125f * 1.44269504f;
  const int qrow = wave * 16 + lq;
  bf16x8 qf[2];
#pragma unroll
  for (int ks = 0; ks < 2; ++ks) {
    const float* qp = Qp + (size_t)qrow * DDIM + 8 * g + 32 * ks;
    f32x4 a = *(const f32x4*)qp;
    f32x4 b = *(const f32x4*)(qp + 4);
    bf16x8 t;
#pragma unroll
    for (int j = 0; j < 4; ++j) { t[j] = (__bf16)(a[j] * QSCALE); t[4 + j] = (__bf16)(b[j] * QSCALE); }
    qf[ks] = t;
  }

  const unsigned char* mrow8 = Mg + ((size_t)head * QLEN + (size_t)qblk * QBLK + qrow) * SLEN;

  f32x4 oacc[4];
#pragma unroll
  for (int vt = 0; vt < 4; ++vt) oacc[vt] = (f32x4){0.f, 0.f, 0.f, 0.f};
  float m_run = -INFINITY;
  float l_run = 0.f;

#define STAGE(CM, BUF) {                                                       \
  int cm_ = (CM); if (cm_ > NCHUNK - 1) cm_ = NCHUNK - 1;                      \
  const unsigned char* s_ = imgh + (size_t)cm_ * IMG_CHUNK_BYTES + wave * 2048 + lane * 16; \
  unsigned char* d_ = &KV[BUF][wave * 2048];                                   \
  gl16(s_,        d_);                                                         \
  gl16(s_ + 1024, d_ + 1024);                                                  \
  gl16(s_ + 8192, d_ + 8192);                                                  \
  gl16(s_ + 9216, d_ + 9216);                                                  \
}

#define LOAD_MASK_F(MS, CM) {                                                  \
  int cm_ = (CM); if (cm_ > NCHUNK - 1) cm_ = NCHUNK - 1;                      \
  size_t mo_ = (size_t)cm_ * SBLK;                                             \
  _Pragma("unroll")                                                            \
  for (int st = 0; st < 4; ++st)                                               \
    MS[st] = *(const unsigned*)(mrow8 + mo_ + 16 * st + 4 * g);                \
}

// Body c: counted wait (never 0) for chunk-c's 8 vmem ops, barrier (+compiler
// fence), then issue c+3's mask+stage (8 vmem ops), then compute. vmcnt(16)
// is order-robust: 2 full younger regions (16 ops) sit behind region c in any
// intra-region issue order, and memory-clobber fences stop cross-region motion.
#define FBODY(C, BUF, MUSE, MLOAD) {                                           \
  asm volatile("s_waitcnt vmcnt(16)" ::: "memory");                            \
  __builtin_amdgcn_s_barrier();                                                \
  asm volatile("" ::: "memory");                                               \
  LOAD_MASK_F(MLOAD, (C) + 3);                                                 \
  STAGE((C) + 3, ((BUF) + 3) & 3);                                             \
  const char* kbase_ = (const char*)KV[BUF];                                   \
  f32x4 sacc[4];                                                               \
  _Pragma("unroll")                                                            \
  for (int st = 0; st < 4; ++st) sacc[st] = (f32x4){0.f, 0.f, 0.f, 0.f};       \
  _Pragma("unroll")                                                            \
  for (int st = 0; st < 4; ++st) {                                             \
    int srow = lq + 16 * st;                                                   \
    _Pragma("unroll")                                                          \
    for (int ks = 0; ks < 2; ++ks) {                                           \
      int off = (srow * 128 + (8 * g + 32 * ks) * 2) ^ ((srow & 7) << 4);      \
      bf16x8 kf = *(const bf16x8*)(kbase_ + off);                              \
      sacc[st] = __builtin_amdgcn_mfma_f32_16x16x32_bf16(kf, qf[ks], sacc[st], 0, 0, 0); \
    }                                                                          \
  }                                                                            \
  float vals[4][4];                                                            \
  float mloc = -INFINITY;                                                      \
  _Pragma("unroll")                                                            \
  for (int st = 0; st < 4; ++st) {                                             \
    _Pragma("unroll")                                                          \
    for (int r = 0; r < 4; ++r) {                                              \
      bool keep = ((MUSE[st] >> (8 * r)) & 0xFFu) != 0u;                       \
      float v = keep ? sacc[st][r] : -1.0e9f;                                  \
      vals[st][r] = v;                                                         \
      mloc = fmaxf(mloc, v);                                                   \
    }                                                                          \
  }                                                                            \
  mloc = fmaxf(mloc, __shfl_xor(mloc, 16));                                    \
  mloc = fmaxf(mloc, __shfl_xor(mloc, 32));                                    \
  float m_new = fmaxf(m_run, mloc);                                            \
  float alpha = __builtin_amdgcn_exp2f(m_run - m_new);                         \
  float lsum = 0.f;                                                            \
  _Pragma("unroll")                                                            \
  for (int st = 0; st < 4; ++st) {                                             \
    bf16x4 pb;                                                                 \
    _Pragma("unroll")                                                          \
    for (int r = 0; r < 4; ++r) {                                              \
      float p = __builtin_amdgcn_exp2f(vals[st][r] - m_new);                   \
      lsum += p;                                                               \
      pb[r] = (__bf16)p;                                                       \
    }                                                                          \
    int poff = (lq * 128 + (16 * st + 4 * g) * 2) ^ ((lq & 7) << 4);           \
    *(u16x4*)((char*)Psh[wave] + poff) = __builtin_bit_cast(u16x4, pb);        \
  }                                                                            \
  lsum += __shfl_xor(lsum, 16);                                                \
  lsum += __shfl_xor(lsum, 32);                                                \
  l_run = l_run * alpha + lsum;                                                \
  m_run = m_new;                                                               \
  _Pragma("unroll")                                                            \
  for (int vt = 0; vt < 4; ++vt) {                                             \
    _Pragma("unroll")                                                          \
    for (int r = 0; r < 4; ++r) oacc[vt][r] *= alpha;                          \
  }                                                                            \
  const char* vbase_ = (const char*)KV[BUF] + 8192;                            \
  _Pragma("unroll")                                                            \
  for (int ks = 0; ks < 2; ++ks) {                                             \
    int poff = (lq * 128 + (8 * g + 32 * ks) * 2) ^ ((lq & 7) << 4);           \
    bf16x8 pf = *(const bf16x8*)((const char*)Psh[wave] + poff);               \
    _Pragma("unroll")                                                          \
    for (int vt = 0; vt < 4; ++vt) {                                           \
      int vrow = lq + 16 * vt;                                                 \
      int voff = (vrow * 128 + (8 * g + 32 * ks) * 2) ^ ((vrow & 7) << 4);     \
      bf16x8 vf = *(const bf16x8*)(vbase_ + voff);                             \
      oacc[vt] = __builtin_amdgcn_mfma_f32_16x16x32_bf16(vf, pf, oacc[vt], 0, 0, 0); \
    }                                                                          \
  }                                                                            \
}

  unsigned mA[4], mB[4], mC[4], mD[4];

  // prologue: 3 regions (8 vmem ops each), fenced so the vmcnt count holds
  __builtin_amdgcn_sched_barrier(0);
  LOAD_MASK_F(mA, 0); STAGE(0, 0);
  asm volatile("" ::: "memory");
  LOAD_MASK_F(mB, 1); STAGE(1, 1);
  asm volatile("" ::: "memory");
  LOAD_MASK_F(mC, 2); STAGE(2, 2);

  for (int cc = 0; cc < NCHUNK; cc += 4) {
    FBODY(cc + 0, 0, mA, mD);
    FBODY(cc + 1, 1, mB, mA);
    FBODY(cc + 2, 2, mC, mB);
    FBODY(cc + 3, 3, mD, mC);
  }

  float inv_l = 1.0f / l_run;
  float* orow = Op + (size_t)qrow * VDIM;
#pragma unroll
  for (int vt = 0; vt < 4; ++vt) {
    f32x4 o;
#pragma unroll
    for (int r = 0; r < 4; ++r) o[r] = oacc[vt][r] * inv_l;
    *(f32x4*)(orow + 16 * vt + 4 * g) = o;
  }
#undef STAGE
#undef LOAD_MASK_F
#undef FBODY
}

// ---------------- fallback (round-3 kernel, self-detecting, gated) ----------------
struct MaskRegs {
  unsigned w8[4];
  u32x4    w32[4];
};

__global__ __launch_bounds__(256, 2)
void attn_fwd_fallback(const float* __restrict__ Qg, const float* __restrict__ Kg,
                       const float* __restrict__ Vg, const unsigned char* __restrict__ Mg,
                       float* __restrict__ Og, int gate)
{
  __shared__ __align__(16) unsigned short Ksh[2][64 * 64];
  __shared__ __align__(16) unsigned short Vsh[2][64 * 64];
  __shared__ __align__(16) unsigned short Psh[NWAVES][16 * 64];

  const int mfmt = detect_mfmt(Mg);
  if (gate && mfmt == 0) return;   // u8 handled by fast kernel

  const int tid  = threadIdx.x;
  const int wave = tid >> 6;
  const int lane = tid & 63;
  const int g    = lane >> 4;
  const int lq   = lane & 15;

  const int head = blockIdx.y;
  const int qblk = blockIdx.x;

  const float* Qp = Qg + ((size_t)head * QLEN + (size_t)qblk * QBLK) * DDIM;
  const float* Kp = Kg + (size_t)head * SLEN * DDIM;
  const float* Vp = Vg + (size_t)head * SLEN * VDIM;
  float* Op = Og + ((size_t)head * QLEN + (size_t)qblk * QBLK) * DDIM;

  const float QSCALE = 0.125f * 1.44269504f;
  const int qrow = wave * 16 + lq;
  bf16x8 qf[2];
#pragma unroll
  for (int ks = 0; ks < 2; ++ks) {
    const float* qp = Qp + (size_t)qrow * DDIM + 8 * g + 32 * ks;
    f32x4 a = *(const f32x4*)qp;
    f32x4 b = *(const f32x4*)(qp + 4);
    bf16x8 t;
#pragma unroll
    for (int j = 0; j < 4; ++j) { t[j] = (__bf16)(a[j] * QSCALE); t[4 + j] = (__bf16)(b[j] * QSCALE); }
    qf[ks] = t;
  }

  const size_t mrow_elems = ((size_t)head * QLEN + (size_t)qblk * QBLK + qrow) * SLEN;
  const unsigned char* mrow8  = Mg + mrow_elems;
  const unsigned*      mrow32 = (const unsigned*)Mg + mrow_elems;

  f32x4 oacc[4];
#pragma unroll
  for (int vt = 0; vt < 4; ++vt) oacc[vt] = (f32x4){0.f, 0.f, 0.f, 0.f};
  float m_run = -INFINITY;
  float l_run = 0.f;

#define PREFETCH_KV(S0)                                                        \
  _Pragma("unroll")                                                            \
  for (int it = 0; it < 4; ++it) {                                             \
    int srow = (tid >> 4) + it * 16;                                           \
    kpre[it] = *(const f32x4*)(Kp + (size_t)((S0) + srow) * DDIM + (tid & 15) * 4); \
  }                                                                            \
  _Pragma("unroll")                                                            \
  for (int it = 0; it < 4; ++it) {                                             \
    int vv = (tid >> 4) + it * 16;                                             \
    const float* vp = Vp + (size_t)((S0) + (tid & 15) * 4) * VDIM + vv;        \
    vpre[it][0] = vp[0]; vpre[it][1] = vp[VDIM];                               \
    vpre[it][2] = vp[2 * VDIM]; vpre[it][3] = vp[3 * VDIM];                    \
  }

#define WRITE_KV(BUF)                                                          \
  _Pragma("unroll")                                                            \
  for (int it = 0; it < 4; ++it) {                                             \
    int srow = (tid >> 4) + it * 16;                                           \
    int d0   = (tid & 15) * 4;                                                 \
    bf16x4 kb;                                                                 \
    _Pragma("unroll") for (int j = 0; j < 4; ++j) kb[j] = (__bf16)kpre[it][j]; \
    int off = (srow * 128 + d0 * 2) ^ ((srow & 7) << 4);                       \
    *(u16x4*)((char*)Ksh[BUF] + off) = __builtin_bit_cast(u16x4, kb);          \
  }                                                                            \
  _Pragma("unroll")                                                            \
  for (int it = 0; it < 4; ++it) {                                             \
    int vv = (tid >> 4) + it * 16;                                             \
    int s4 = (tid & 15) * 4;                                                   \
    bf16x4 vb;                                                                 \
    _Pragma("unroll") for (int j = 0; j < 4; ++j) vb[j] = (__bf16)vpre[it][j]; \
    int off = (vv * 128 + s4 * 2) ^ ((vv & 7) << 4);                           \
    *(u16x4*)((char*)Vsh[BUF] + off) = __builtin_bit_cast(u16x4, vb);          \
  }

#define LOAD_MASK(MR, S0)                                                      \
  if (mfmt == 0) {                                                             \
    _Pragma("unroll")                                                          \
    for (int st = 0; st < 4; ++st)                                             \
      MR.w8[st] = *(const unsigned*)(mrow8 + (S0) + 16 * st + 4 * g);          \
  } else {                                                                     \
    _Pragma("unroll")                                                          \
    for (int st = 0; st < 4; ++st)                                             \
      MR.w32[st] = *(const u32x4*)(mrow32 + (S0) + 16 * st + 4 * g);           \
  }

#define CHUNK_BODY(C, CUR, MUSE, MLOAD) {                                      \
  const bool hasn = ((C) + 1 < NCHUNK);                                        \
  f32x4 kpre[4]; float vpre[4][4];                                             \
  if (hasn) {                                                                  \
    const int s0n = ((C) + 1) * SBLK;                                          \
    PREFETCH_KV(s0n);                                                          \
    LOAD_MASK(MLOAD, s0n);                                                     \
  }                                                                            \
  f32x4 sacc[4];                                                               \
  _Pragma("unroll")                                                            \
  for (int st = 0; st < 4; ++st) sacc[st] = (f32x4){0.f, 0.f, 0.f, 0.f};       \
  _Pragma("unroll")                                                            \
  for (int st = 0; st < 4; ++st) {                                             \
    int srow = lq + 16 * st;                                                   \
    _Pragma("unroll")                                                          \
    for (int ks = 0; ks < 2; ++ks) {                                           \
      int off = (srow * 128 + (8 * g + 32 * ks) * 2) ^ ((srow & 7) << 4);      \
      bf16x8 kf = *(const bf16x8*)((const char*)Ksh[CUR] + off);               \
      sacc[st] = __builtin_amdgcn_mfma_f32_16x16x32_bf16(kf, qf[ks], sacc[st], 0, 0, 0); \
    }                                                                          \
  }                                                                            \
  float vals[4][4];                                                            \
  float mloc = -INFINITY;                                                      \
  _Pragma("unroll")                                                            \
  for (int st = 0; st < 4; ++st) {                                             \
    bool keep[4];                                                              \
    if (mfmt == 0) {                                                           \
      _Pragma("unroll")                                                        \
      for (int r = 0; r < 4; ++r) keep[r] = ((MUSE.w8[st] >> (8 * r)) & 0xFFu) != 0u; \
    } else {                                                                   \
      _Pragma("unroll")                                                        \
      for (int r = 0; r < 4; ++r) keep[r] = MUSE.w32[st][r] != 0u;             \
    }                                                                          \
    _Pragma("unroll")                                                          \
    for (int r = 0; r < 4; ++r) {                                              \
      float v = keep[r] ? sacc[st][r] : -1.0e9f;                               \
      vals[st][r] = v;                                                         \
      mloc = fmaxf(mloc, v);                                                   \
    }                                                                          \
  }                                                                            \
  mloc = fmaxf(mloc, __shfl_xor(mloc, 16));                                    \
  mloc = fmaxf(mloc, __shfl_xor(mloc, 32));                                    \
  float m_new = fmaxf(m_run, mloc);                                            \
  float alpha = __builtin_amdgcn_exp2f(m_run - m_new);                         \
  float lsum = 0.f;                                                            \
  _Pragma("unroll")                                                            \
  for (int st = 0; st < 4; ++st) {                                             \
    bf16x4 pb;                                                                 \
    _Pragma("unroll")                                                          \
    for (int r = 0; r < 4; ++r) {                                              \
      float p = __builtin_amdgcn_exp2f(vals[st][r] - m_new);                   \
      lsum += p;                                                               \
      pb[r] = (__bf16)p;                                                       \
    }                                                                          \
    int off = (lq * 128 + (16 * st + 4 * g) * 2) ^ ((lq & 7) << 4);            \
    *(u16x4*)((char*)Psh[wave] + off) = __builtin_bit_cast(u16x4, pb);         \
  }                                                                            \
  lsum += __shfl_xor(lsum, 16);                                                \
  lsum += __shfl_xor(lsum, 32);                                                \
  l_run = l_run * alpha + lsum;                                                \
  m_run = m_new;                                                               \
  _Pragma("unroll")                                                            \
  for (int vt = 0; vt < 4; ++vt) {                                             \
    _Pragma("unroll")                                                          \
    for (int r = 0; r < 4; ++r) oacc[vt][r] *= alpha;                          \
  }                                                                            \
  _Pragma("unroll")                                                            \
  for (int ks = 0; ks < 2; ++ks) {                                             \
    int poff = (lq * 128 + (8 * g + 32 * ks) * 2) ^ ((lq & 7) << 4);           \
    bf16x8 pf = *(const bf16x8*)((const char*)Psh[wave] + poff);               \
    _Pragma("unroll")                                                          \
    for (int vt = 0; vt < 4; ++vt) {                                           \
      int vrow = lq + 16 * vt;                                                 \
      int voff = (vrow * 128 + (8 * g + 32 * ks) * 2) ^ ((vrow & 7) << 4);     \
      bf16x8 vf = *(const bf16x8*)((const char*)Vsh[CUR] + voff);              \
      oacc[vt] = __builtin_amdgcn_mfma_f32_16x16x32_bf16(vf, pf, oacc[vt], 0, 0, 0); \
    }                                                                          \
  }                                                                            \
  if (hasn) { WRITE_KV((CUR) ^ 1); }                                           \
  __syncthreads();                                                             \
}

  MaskRegs mA, mB;
  {
    f32x4 kpre[4]; float vpre[4][4];
    PREFETCH_KV(0);
    LOAD_MASK(mA, 0);
    WRITE_KV(0);
    __syncthreads();
  }
  for (int cc = 0; cc < NCHUNK; cc += 2) {
    CHUNK_BODY(cc,     0, mA, mB);
    CHUNK_BODY(cc + 1, 1, mB, mA);
  }

  float inv_l = 1.0f / l_run;
  float* orow = Op + (size_t)qrow * VDIM;
#pragma unroll
  for (int vt = 0; vt < 4; ++vt) {
    f32x4 o;
#pragma unroll
    for (int r = 0; r < 4; ++r) o[r] = oacc[vt][r] * inv_l;
    *(f32x4*)(orow + 16 * vt + 4 * g) = o;
  }
#undef PREFETCH_KV
#undef WRITE_KV
#undef LOAD_MASK
#undef CHUNK_BODY
}

extern "C" void kernel_launch(void* const* d_in, const int* in_sizes, int n_in,
                              void* d_out, int out_size, void* d_ws, size_t ws_size,
                              hipStream_t stream) {
  const float* Qg = (const float*)d_in[0];
  const float* Kg = (const float*)d_in[1];
  const float* Vg = (const float*)d_in[2];
  const unsigned char* Mg = (const unsigned char*)d_in[3];
  float* Og = (float*)d_out;
  unsigned char* img = (unsigned char*)d_ws;
  const size_t need = (size_t)NHEADS * NCHUNK * IMG_CHUNK_BYTES;   // exactly 8 MiB

  if (ws_size >= need) {
    prepack_kv<<<dim3(NCHUNK, NHEADS), 256, 0, stream>>>(Kg, Vg, img);
    attn_fwd_fast<<<dim3(NHEADS, QLEN / QBLK), 256, 0, stream>>>(Qg, Mg, img, Og);
    // safety net: runs only if mask is not u8
    attn_fwd_fallback<<<dim3(QLEN / QBLK, NHEADS), 256, 0, stream>>>(Qg, Kg, Vg, Mg, Og, 1);
  } else {
    attn_fwd_fallback<<<dim3(QLEN / QBLK, NHEADS), 256, 0, stream>>>(Qg, Kg, Vg, Mg, Og, 0);
  }
}

// Round 6
// 155.181 us; speedup vs baseline: 2.1976x; 2.1391x over previous
//
#include <hip/hip_runtime.h>
#include <hip/hip_bf16.h>

// Flash attention fwd, masked, fp32 I/O, bf16 MFMA compute.
// n=8 heads, q=s=4096, d=v=64.
// S^T = K·Q^T (lane owns one q-column); PV computes O^T = V^T·P^T.
// Round 6: no-workspace single kernel. V global loads made COALESCED
// (f32x4, same as K) with the transpose moved to LDS write side
// (16x ds_write_b16, row-swizzle ((v>>2)&7)<<4 => ~4-way conflicts only).
// Grid (head, qblk): linear%8 == head pins each head to one XCD so its
// 2MB K/V stays L2-resident. Double-buffered LDS, 1 barrier/chunk,
// K/V+mask prefetched 1 chunk ahead in registers.

#define NHEADS 8
#define QLEN   4096
#define SLEN   4096
#define DDIM   64
#define VDIM   64
#define SBLK   64
#define QBLK   64
#define NWAVES 4
#define NCHUNK (SLEN / SBLK)

typedef __bf16          bf16x4 __attribute__((ext_vector_type(4)));
typedef __bf16          bf16x8 __attribute__((ext_vector_type(8)));
typedef float           f32x4  __attribute__((ext_vector_type(4)));
typedef unsigned int    u32x4  __attribute__((ext_vector_type(4)));
typedef unsigned short  u16x4  __attribute__((ext_vector_type(4)));

// row-swizzles (byte-offset XOR, multiples of 16 so 16B chunks stay intact)
#define KSWZ(s) (((s) & 7) << 4)
#define VSWZ(v) ((((v) >> 2) & 7) << 4)

// ---------------- in-kernel mask dtype detection ----------------
// Wave-cooperative scan of the mask's first 1KB (64 lanes x 16B).
// i32 {0,1}: bytes 1,2 of every word zero -> 1.
// f32 {0,1.0f}: byte 0 of every word zero (0x3F800000 LE) -> 2.
// u8 bool: neither -> 0. Uniform across all lanes/waves/blocks.
__device__ __forceinline__ int detect_mfmt(const unsigned char* __restrict__ M) {
  const int lane = threadIdx.x & 63;
  u32x4 w = *((const u32x4*)M + lane);
  unsigned o = w[0] | w[1] | w[2] | w[3];
  unsigned comb = ((o & 0x00FFFF00u) ? 1u : 0u) | ((o & 0x000000FFu) ? 2u : 0u);
  comb |= __shfl_xor((int)comb, 1);  comb |= __shfl_xor((int)comb, 2);
  comb |= __shfl_xor((int)comb, 4);  comb |= __shfl_xor((int)comb, 8);
  comb |= __shfl_xor((int)comb, 16); comb |= __shfl_xor((int)comb, 32);
  return ((comb & 1u) == 0u) ? 1 : (((comb & 2u) == 0u) ? 2 : 0);
}

struct MaskRegs {
  unsigned w8[4];
  u32x4    w32[4];
};

__global__ __launch_bounds__(256, 2)
void attn_fwd_kernel(const float* __restrict__ Qg, const float* __restrict__ Kg,
                     const float* __restrict__ Vg, const unsigned char* __restrict__ Mg,
                     float* __restrict__ Og)
{
  __shared__ __align__(16) unsigned short Ksh[2][64 * 64];       // [s][d], KSWZ rows
  __shared__ __align__(16) unsigned short Vsh[2][64 * 64];       // [v][s], VSWZ rows
  __shared__ __align__(16) unsigned short Psh[NWAVES][16 * 64];  // [q][s] per wave

  const int mfmt = detect_mfmt(Mg);

  const int tid  = threadIdx.x;
  const int wave = tid >> 6;
  const int lane = tid & 63;
  const int g    = lane >> 4;
  const int lq   = lane & 15;

  const int head = blockIdx.x;    // grid (8, 64): linear id % 8 == head -> one XCD per head
  const int qblk = blockIdx.y;

  const float* Qp = Qg + ((size_t)head * QLEN + (size_t)qblk * QBLK) * DDIM;
  const float* Kp = Kg + (size_t)head * SLEN * DDIM;
  const float* Vp = Vg + (size_t)head * SLEN * VDIM;
  float* Op = Og + ((size_t)head * QLEN + (size_t)qblk * QBLK) * DDIM;

  // Q fragments, pre-scaled by (1/sqrt(d))*log2(e)
  const float QSCALE = 0.125f * 1.44269504f;
  const int qrow = wave * 16 + lq;
  bf16x8 qf[2];
#pragma unroll
  for (int ks = 0; ks < 2; ++ks) {
    const float* qp = Qp + (size_t)qrow * DDIM + 8 * g + 32 * ks;
    f32x4 a = *(const f32x4*)qp;
    f32x4 b = *(const f32x4*)(qp + 4);
    bf16x8 t;
#pragma unroll
    for (int j = 0; j < 4; ++j) { t[j] = (__bf16)(a[j] * QSCALE); t[4 + j] = (__bf16)(b[j] * QSCALE); }
    qf[ks] = t;
  }

  const size_t mrow_elems = ((size_t)head * QLEN + (size_t)qblk * QBLK + qrow) * SLEN;
  const unsigned char* mrow8  = Mg + mrow_elems;
  const unsigned*      mrow32 = (const unsigned*)Mg + mrow_elems;

  f32x4 oacc[4];
#pragma unroll
  for (int vt = 0; vt < 4; ++vt) oacc[vt] = (f32x4){0.f, 0.f, 0.f, 0.f};
  float m_run = -INFINITY;
  float l_run = 0.f;

  // Both K and V prefetches are fully coalesced f32x4 row loads.
#define PREFETCH_KV(S0)                                                        \
  _Pragma("unroll")                                                            \
  for (int it = 0; it < 4; ++it) {                                             \
    int srow = (tid >> 4) + it * 16;                                           \
    int d0   = (tid & 15) * 4;                                                 \
    kpre[it] = *(const f32x4*)(Kp + (size_t)((S0) + srow) * DDIM + d0);        \
    vpre[it] = *(const f32x4*)(Vp + (size_t)((S0) + srow) * VDIM + d0);        \
  }

  // K: b64 writes, rows s (KSWZ). V: transposed scatter, 16x b16 into rows
  // v=d0+j (VSWZ -> 4-way bank aliasing only).
#define WRITE_KV(BUF)                                                          \
  _Pragma("unroll")                                                            \
  for (int it = 0; it < 4; ++it) {                                             \
    int srow = (tid >> 4) + it * 16;                                           \
    int d0   = (tid & 15) * 4;                                                 \
    bf16x4 kb;                                                                 \
    _Pragma("unroll") for (int j = 0; j < 4; ++j) kb[j] = (__bf16)kpre[it][j]; \
    int koff = (srow * 128 + d0 * 2) ^ KSWZ(srow);                             \
    *(u16x4*)((char*)Ksh[BUF] + koff) = __builtin_bit_cast(u16x4, kb);         \
    _Pragma("unroll")                                                          \
    for (int j = 0; j < 4; ++j) {                                              \
      int v = d0 + j;                                                          \
      unsigned short b = __builtin_bit_cast(unsigned short, (__bf16)vpre[it][j]); \
      int voff = (v * 128 + srow * 2) ^ VSWZ(v);                               \
      *(unsigned short*)((char*)Vsh[BUF] + voff) = b;                          \
    }                                                                          \
  }

#define LOAD_MASK(MR, S0)                                                      \
  if (mfmt == 0) {                                                             \
    _Pragma("unroll")                                                          \
    for (int st = 0; st < 4; ++st)                                             \
      MR.w8[st] = *(const unsigned*)(mrow8 + (S0) + 16 * st + 4 * g);          \
  } else {                                                                     \
    _Pragma("unroll")                                                          \
    for (int st = 0; st < 4; ++st)                                             \
      MR.w32[st] = *(const u32x4*)(mrow32 + (S0) + 16 * st + 4 * g);           \
  }

#define CHUNK_BODY(C, CUR, MUSE, MLOAD) {                                      \
  const bool hasn = ((C) + 1 < NCHUNK);                                        \
  f32x4 kpre[4]; f32x4 vpre[4];                                                \
  if (hasn) {                                                                  \
    const int s0n = ((C) + 1) * SBLK;                                          \
    PREFETCH_KV(s0n);                                                          \
    LOAD_MASK(MLOAD, s0n);                                                     \
  }                                                                            \
  /* QK^T: S^T tiles (A = K rows-of-s, B = Q^T) */                             \
  f32x4 sacc[4];                                                               \
  _Pragma("unroll")                                                            \
  for (int st = 0; st < 4; ++st) sacc[st] = (f32x4){0.f, 0.f, 0.f, 0.f};       \
  _Pragma("unroll")                                                            \
  for (int st = 0; st < 4; ++st) {                                             \
    int srow = lq + 16 * st;                                                   \
    _Pragma("unroll")                                                          \
    for (int ks = 0; ks < 2; ++ks) {                                           \
      int off = (srow * 128 + (8 * g + 32 * ks) * 2) ^ KSWZ(srow);             \
      bf16x8 kf = *(const bf16x8*)((const char*)Ksh[CUR] + off);               \
      sacc[st] = __builtin_amdgcn_mfma_f32_16x16x32_bf16(kf, qf[ks], sacc[st], 0, 0, 0); \
    }                                                                          \
  }                                                                            \
  /* mask + chunk max (lane scores: s = 16st+4g+r, q=lq) */                    \
  float vals[4][4];                                                            \
  float mloc = -INFINITY;                                                      \
  _Pragma("unroll")                                                            \
  for (int st = 0; st < 4; ++st) {                                             \
    bool keep[4];                                                              \
    if (mfmt == 0) {                                                           \
      _Pragma("unroll")                                                        \
      for (int r = 0; r < 4; ++r) keep[r] = ((MUSE.w8[st] >> (8 * r)) & 0xFFu) != 0u; \
    } else {                                                                   \
      _Pragma("unroll")                                                        \
      for (int r = 0; r < 4; ++r) keep[r] = MUSE.w32[st][r] != 0u;             \
    }                                                                          \
    _Pragma("unroll")                                                          \
    for (int r = 0; r < 4; ++r) {                                              \
      float v = keep[r] ? sacc[st][r] : -1.0e9f;                               \
      vals[st][r] = v;                                                         \
      mloc = fmaxf(mloc, v);                                                   \
    }                                                                          \
  }                                                                            \
  mloc = fmaxf(mloc, __shfl_xor(mloc, 16));                                    \
  mloc = fmaxf(mloc, __shfl_xor(mloc, 32));                                    \
  float m_new = fmaxf(m_run, mloc);                                            \
  float alpha = __builtin_amdgcn_exp2f(m_run - m_new);                         \
  float lsum = 0.f;                                                            \
  _Pragma("unroll")                                                            \
  for (int st = 0; st < 4; ++st) {                                             \
    bf16x4 pb;                                                                 \
    _Pragma("unroll")                                                          \
    for (int r = 0; r < 4; ++r) {                                              \
      float p = __builtin_amdgcn_exp2f(vals[st][r] - m_new);                   \
      lsum += p;                                                               \
      pb[r] = (__bf16)p;                                                       \
    }                                                                          \
    int off = (lq * 128 + (16 * st + 4 * g) * 2) ^ KSWZ(lq);                   \
    *(u16x4*)((char*)Psh[wave] + off) = __builtin_bit_cast(u16x4, pb);         \
  }                                                                            \
  lsum += __shfl_xor(lsum, 16);                                                \
  lsum += __shfl_xor(lsum, 32);                                                \
  l_run = l_run * alpha + lsum;                                                \
  m_run = m_new;                                                               \
  _Pragma("unroll")                                                            \
  for (int vt = 0; vt < 4; ++vt) {                                             \
    _Pragma("unroll")                                                          \
    for (int r = 0; r < 4; ++r) oacc[vt][r] *= alpha;                          \
  }                                                                            \
  /* PV: O^T += V^T_tile · P^T */                                              \
  _Pragma("unroll")                                                            \
  for (int ks = 0; ks < 2; ++ks) {                                             \
    int poff = (lq * 128 + (8 * g + 32 * ks) * 2) ^ KSWZ(lq);                  \
    bf16x8 pf = *(const bf16x8*)((const char*)Psh[wave] + poff);               \
    _Pragma("unroll")                                                          \
    for (int vt = 0; vt < 4; ++vt) {                                           \
      int vrow = lq + 16 * vt;                                                 \
      int voff = (vrow * 128 + (8 * g + 32 * ks) * 2) ^ VSWZ(vrow);            \
      bf16x8 vf = *(const bf16x8*)((const char*)Vsh[CUR] + voff);              \
      oacc[vt] = __builtin_amdgcn_mfma_f32_16x16x32_bf16(vf, pf, oacc[vt], 0, 0, 0); \
    }                                                                          \
  }                                                                            \
  if (hasn) { WRITE_KV((CUR) ^ 1); }                                           \
  __syncthreads();                                                             \
}

  MaskRegs mA, mB;

  // prologue: stage chunk 0 directly, load its mask
  {
    f32x4 kpre[4]; f32x4 vpre[4];
    PREFETCH_KV(0);
    LOAD_MASK(mA, 0);
    WRITE_KV(0);
    __syncthreads();
  }

  for (int cc = 0; cc < NCHUNK; cc += 2) {
    CHUNK_BODY(cc,     0, mA, mB);
    CHUNK_BODY(cc + 1, 1, mB, mA);
  }

  // epilogue: O = O^T(v,q)/l, store fp32 (lane: q=lq, v=16vt+4g+r)
  float inv_l = 1.0f / l_run;
  float* orow = Op + (size_t)qrow * VDIM;
#pragma unroll
  for (int vt = 0; vt < 4; ++vt) {
    f32x4 o;
#pragma unroll
    for (int r = 0; r < 4; ++r) o[r] = oacc[vt][r] * inv_l;
    *(f32x4*)(orow + 16 * vt + 4 * g) = o;
  }
}

extern "C" void kernel_launch(void* const* d_in, const int* in_sizes, int n_in,
                              void* d_out, int out_size, void* d_ws, size_t ws_size,
                              hipStream_t stream) {
  const float* Qg = (const float*)d_in[0];
  const float* Kg = (const float*)d_in[1];
  const float* Vg = (const float*)d_in[2];
  const unsigned char* Mg = (const unsigned char*)d_in[3];
  float* Og = (float*)d_out;

  dim3 grid(NHEADS, QLEN / QBLK);   // linear id % 8 == head -> head-per-XCD
  dim3 block(256);
  attn_fwd_kernel<<<grid, block, 0, stream>>>(Qg, Kg, Vg, Mg, Og);
}